// Round 1
// baseline (709.509 us; speedup 1.0000x reference)
//
#include <hip/hip_runtime.h>

// LocallyConnected1d: out[b,o,l] = sum_{c,k} x[b,c,l+k] * w[o,c,l,k] + bias[o,l]
// B=32, Cin=Cout=128, L=2048, K=3, S=1, W=2050. All fp32.
//
// Memory-bound on weight (403 MB, used once per batch-set). Each block owns a
// 16(o) x 16(l) tile across ALL 32 batches -> weight crosses HBM exactly once.
// Per-thread register tile: 4(b) x 2(o) x 4(l) = 32 accumulators.

constexpr int CIN  = 128;
constexpr int COUT = 128;
constexpr int LL   = 2048;
constexpr int WID  = 2050;
constexpr int BATCH = 32;
constexpr int KK   = 3;

constexpr int O_TILE = 16;
constexpr int L_TILE = 16;
constexpr int CB = 4;            // channels staged per outer iteration
constexpr int TB = 4;            // batches per thread
constexpr int TO = 2;            // outputs per thread
constexpr int TL = 4;            // locations per thread
constexpr int J_USE = L_TILE + 2;  // 18 x-values per (c,b) row
constexpr int J_PAD = 24;          // padded row stride (96 B -> 16B-aligned rows)
constexpr int STAGE_PER_THREAD = (CB * BATCH * J_USE) / 256;  // 9

__global__ __launch_bounds__(256, 4)
void lc1d(const float* __restrict__ x, const float* __restrict__ w,
          const float* __restrict__ bias, float* __restrict__ out) {
  __shared__ float xs[CB * BATCH * J_PAD];  // 12 KB

  const int tid = threadIdx.x;
  const int lg = tid & 3;          // l-group: 4 groups of TL=4
  const int og = (tid >> 2) & 7;   // o-group: 8 groups of TO=2
  const int bg = tid >> 5;         // b-group: 8 groups of TB=4

  const int bx = blockIdx.x;
  const int ltile = bx & 127;      // 128 l-tiles
  const int otile = bx >> 7;       // 8 o-tiles
  const int L0 = ltile * L_TILE;
  const int o_base = otile * O_TILE + og * TO;
  const int l_base = L0 + lg * TL;
  const int b_base = bg * TB;

  // --- accumulators, initialized with bias (same bias for every batch) ---
  float acc[TB][TO][TL];
  #pragma unroll
  for (int oi = 0; oi < TO; ++oi) {
    const float4 bv =
        *reinterpret_cast<const float4*>(&bias[(o_base + oi) * LL + l_base]);
    #pragma unroll
    for (int bi = 0; bi < TB; ++bi) {
      acc[bi][oi][0] = bv.x; acc[bi][oi][1] = bv.y;
      acc[bi][oi][2] = bv.z; acc[bi][oi][3] = bv.w;
    }
  }

  // --- precompute x-staging assignments (fixed per thread) ---
  // 2304 useful dwords per stage / 256 threads = 9 each.
  int g_off[STAGE_PER_THREAD];  // dword offset into x (advances by CB*WID)
  int l_off[STAGE_PER_THREAD];  // dword offset into xs (fixed)
  #pragma unroll
  for (int i = 0; i < STAGE_PER_THREAD; ++i) {
    const int u  = tid + 256 * i;
    const int cs = u / (BATCH * J_USE);
    const int r  = u - cs * (BATCH * J_USE);
    const int b  = r / J_USE;
    const int j  = r - b * J_USE;
    g_off[i] = (b * CIN + cs) * WID + L0 + j;
    l_off[i] = (cs * BATCH + b) * J_PAD + j;
  }

  // weight dword offsets for (o_base+oi, c=0, l=l_base, k=0)
  int w_off[TO];
  #pragma unroll
  for (int oi = 0; oi < TO; ++oi)
    w_off[oi] = (o_base + oi) * (CIN * LL * KK) + l_base * KK;

  for (int c0 = 0; c0 < CIN; c0 += CB) {
    __syncthreads();  // WAR: previous compute phase done before overwrite
    #pragma unroll
    for (int i = 0; i < STAGE_PER_THREAD; ++i) {
      xs[l_off[i]] = x[g_off[i]];
      g_off[i] += CB * WID;
    }
    __syncthreads();

    #pragma unroll
    for (int cs = 0; cs < CB; ++cs) {
      // 12 consecutive weight dwords per (o): w[o, c0+cs, l_base..l_base+3, 0..2]
      float4 wv[TO][3];
      #pragma unroll
      for (int oi = 0; oi < TO; ++oi) {
        const float* wp = w + (w_off[oi] + cs * (LL * KK));
        wv[oi][0] = *reinterpret_cast<const float4*>(wp);
        wv[oi][1] = *reinterpret_cast<const float4*>(wp + 4);
        wv[oi][2] = *reinterpret_cast<const float4*>(wp + 8);
      }
      #pragma unroll
      for (int bi = 0; bi < TB; ++bi) {
        const float* xr =
            &xs[(cs * BATCH + (b_base + bi)) * J_PAD + lg * TL];
        const float4 xa = *reinterpret_cast<const float4*>(xr);      // ds_read_b128
        const float2 xb = *reinterpret_cast<const float2*>(xr + 4);  // ds_read_b64
        const float xv[6] = {xa.x, xa.y, xa.z, xa.w, xb.x, xb.y};
        #pragma unroll
        for (int oi = 0; oi < TO; ++oi) {
          const float* wf = reinterpret_cast<const float*>(&wv[oi][0]);
          #pragma unroll
          for (int j = 0; j < TL; ++j) {
            #pragma unroll
            for (int k = 0; k < KK; ++k)
              acc[bi][oi][j] = fmaf(wf[j * KK + k], xv[j + k], acc[bi][oi][j]);
          }
        }
      }
    }
    #pragma unroll
    for (int oi = 0; oi < TO; ++oi) w_off[oi] += CB * (LL * KK);
  }

  // --- store: out[b, o, l_base..l_base+3] as float4 ---
  #pragma unroll
  for (int bi = 0; bi < TB; ++bi) {
    const int b = b_base + bi;
    #pragma unroll
    for (int oi = 0; oi < TO; ++oi) {
      const float4 v = make_float4(acc[bi][oi][0], acc[bi][oi][1],
                                   acc[bi][oi][2], acc[bi][oi][3]);
      *reinterpret_cast<float4*>(&out[(b * COUT + (o_base + oi)) * LL + l_base]) = v;
    }
  }
}

extern "C" void kernel_launch(void* const* d_in, const int* in_sizes, int n_in,
                              void* d_out, int out_size, void* d_ws, size_t ws_size,
                              hipStream_t stream) {
  const float* x    = (const float*)d_in[0];
  const float* wgt  = (const float*)d_in[1];
  const float* bias = (const float*)d_in[2];
  float* out = (float*)d_out;
  // 8 o-tiles x 128 l-tiles = 1024 blocks of 256 threads (4 blocks/CU, all resident)
  hipLaunchKernelGGL(lc1d, dim3(1024), dim3(256), 0, stream, x, wgt, bias, out);
}